// Round 10
// baseline (213.270 us; speedup 1.0000x reference)
//
#include <hip/hip_runtime.h>

#define BB   8
#define CC   128
#define HH   64
#define WW   64
#define HWW  (HH * WW)      // 4096
#define OFFC 18
#define PP   128            // deform output channels
#define KK9  9

typedef __attribute__((ext_vector_type(8))) short bf16x8;
typedef __attribute__((ext_vector_type(4))) float f32x4;

// round-to-nearest-even fp32 -> bf16 bits
__device__ __forceinline__ unsigned bf16_rtne(float v) {
  unsigned u = __float_as_uint(v);
  return (u + 0x7fffu + ((u >> 16) & 1u)) >> 16;
}

// ---------------------------------------------------------------------------
// Kernel A (fused prep):
//  blocks 0..511   : transpose x [B][C][H][W] -> xt [B][H][W][C], XCD-aware
//                    (b = bid&7 so xt[b] is produced on the XCD that will
//                    consume it in k_deform_mfma).
//  blocks 512..583 : pack deform weight into per-lane MFMA A-fragments,
//                    hi/lo bf16 split. K = tap*128 + c (tap-major).
//                    A-frag (16x16x32): lane l holds A[o=l&15][k=(l>>4)*8+j].
//                    Out: [kstep 36][otile 8][lane 64][8].
// ---------------------------------------------------------------------------
__global__ __launch_bounds__(256) void k_prep(
    const float* __restrict__ x, float* __restrict__ xt,
    const float* __restrict__ dfw,   // [P][C][3][3]
    short* __restrict__ whi, short* __restrict__ wlo) {
  const int t = threadIdx.x;
  if (blockIdx.x < 512) {
    __shared__ float s[CC][WW + 1];   // +1 pad
    const int b  = blockIdx.x & 7;    // XCD-local batch
    const int hh = blockIdx.x >> 3;
    const float* xp = x + (size_t)b * CC * HWW + hh * WW;
    const int w = t & 63;
#pragma unroll
    for (int p = 0; p < 32; ++p) {
      int c = p * 4 + (t >> 6);
      s[c][w] = xp[(size_t)c * HWW + w];   // coalesced 64-float rows
    }
    __syncthreads();
    float* op = xt + ((size_t)(b * HH + hh) * WW) * CC;
#pragma unroll
    for (int p = 0; p < 8; ++p) {
      int flat = p * 256 + t;            // 2048 float4 stores
      int ww = flat >> 5, cg = flat & 31;
      float4 v = make_float4(s[cg * 4][ww], s[cg * 4 + 1][ww],
                             s[cg * 4 + 2][ww], s[cg * 4 + 3][ww]);
      *(float4*)&op[ww * CC + cg * 4] = v;  // coalesced
    }
  } else {
    int tid = (blockIdx.x - 512) * 256 + t;  // 36*8*64 = 18432
    if (tid >= 36 * 8 * 64) return;
    int l  = tid & 63;
    int ot = (tid >> 6) & 7;
    int s  = tid >> 9;                 // kstep 0..35
    int o  = ot * 16 + (l & 15);
    bf16x8 hv, lv;
#pragma unroll
    for (int j = 0; j < 8; ++j) {
      int K   = s * 32 + (l >> 4) * 8 + j;
      int tap = K >> 7;
      int c   = K & 127;
      float v = dfw[((size_t)o * CC + c) * KK9 + tap];
      unsigned hb = bf16_rtne(v);
      float lo = v - __uint_as_float(hb << 16);
      hv[j] = (short)hb;
      lv[j] = (short)bf16_rtne(lo);
    }
    *(bf16x8*)&whi[(size_t)tid * 8] = hv;
    *(bf16x8*)&wlo[(size_t)tid * 8] = lv;
  }
}

// ---------------------------------------------------------------------------
// Kernel C: fully fused dwconv+BN+ReLU + offset 1x1 + deformable conv.
// XCD-aware decomposition: b = blockIdx&7, row = blockIdx>>3 — all 64 blocks
// of one batch run on one XCD (4 MB L2 holds x[b]+xt[b]).  [verified r8:
// FETCH 157->18.8 MB]
// LDS layout for the sampled tile S is GRANULE-MAJOR: S[g][r] where
// g = 16B channel-granule (0..15), r = w column (0..63).
//   - write inst: wave-uniform g, r=lane -> 1024B contiguous, even 8/bank
//   - read inst (wt,cstep): four 256B quarter-wave blocks, wave covers
//     1024B evenly -> both at the wave64-b128 throughput minimum
// (replaces the r2 XOR swizzle whose r*256 row stride left every row at
//  bank 0 -> 8-way conflicts on BOTH writes and reads = the 135us floor)
// ---------------------------------------------------------------------------
__global__ __launch_bounds__(256) void k_deform_mfma(
    const float* __restrict__ x,     // [B][C][H][W]  (for dwconv)
    const float* __restrict__ xt,    // [B][H][W][C]  (for gathers)
    const float* __restrict__ dww,   // [C][1][3][3]
    const float* __restrict__ dwb,
    const float* __restrict__ gamma,
    const float* __restrict__ beta,
    const float* __restrict__ mean,
    const float* __restrict__ var,
    const float* __restrict__ ow,    // [18][128]
    const short* __restrict__ whi,   // packed A hi
    const short* __restrict__ wlo,   // packed A lo
    float* __restrict__ out) {       // [B][P][H][W]
  __shared__ union {
    struct {
      float part[4][OFFC][WW];   // 18432 B
      float ow[OFFC * CC];       //  9216 B
      float dww[CC * KK9];       //  4608 B
      float scale[CC];           //   512 B
      float shift[CC];           //   512 B
    } pre;                                        // 33280 B
    struct { short hi[8192]; short lo[8192]; } S; // 32768 B
  } sm;
  __shared__ int4   s_bidx[576];   // 9216 B
  __shared__ float4 s_bwt[576];    // 9216 B
  // total LDS: 51712 B

  const int t = threadIdx.x;
  const int b   = blockIdx.x & 7;   // XCD-local batch
  const int row = blockIdx.x >> 3;

  // ---- phase -1: stage small weights ----
  for (int i = t; i < CC * KK9; i += 256) sm.pre.dww[i] = dww[i];
  for (int i = t; i < OFFC * CC; i += 256) sm.pre.ow[i] = ow[i];
  if (t < CC) {
    float sc = gamma[t] * rsqrtf(var[t] + 1e-5f);
    sm.pre.scale[t] = sc;
    sm.pre.shift[t] = (dwb[t] - mean[t]) * sc + beta[t];
  }
  __syncthreads();

  // ---- phase 0: h (inline dwconv+bn+relu) -> offset 1x1 partials ----
  {
    const int w = t & 63, cg = t >> 6;   // cg wave-uniform
    const float* xb = x + (size_t)b * CC * HWW;
    float accO[OFFC];
#pragma unroll
    for (int o = 0; o < OFFC; ++o) accO[o] = 0.0f;
    for (int cc = 0; cc < 32; ++cc) {
      int c = cg * 32 + cc;
      const float* xc = xb + (size_t)c * HWW;
      float conv = 0.0f;
#pragma unroll
      for (int ky = 0; ky < 3; ++ky) {
        int y = row - 1 + ky;
        if (y < 0 || y >= HH) continue;       // block-uniform branch
        const float* xr = xc + y * WW;
#pragma unroll
        for (int kx = 0; kx < 3; ++kx) {
          int ww2 = w - 1 + kx;
          float xv = (ww2 >= 0 && ww2 < WW) ? xr[ww2 & 63] : 0.0f;
          conv = fmaf(xv, sm.pre.dww[c * KK9 + ky * 3 + kx], conv);
        }
      }
      float hv = fmaxf(fmaf(conv, sm.pre.scale[c], sm.pre.shift[c]), 0.0f);
#pragma unroll
      for (int o = 0; o < OFFC; ++o)
        accO[o] = fmaf(hv, sm.pre.ow[o * CC + c], accO[o]);
    }
#pragma unroll
    for (int o = 0; o < OFFC; ++o) sm.pre.part[cg][o][w] = accO[o];
  }
  __syncthreads();

  // ---- phase 1: reduce partials, build bilinear tables (NHWC indices) ----
  for (int i = t; i < 576; i += 256) {
    int k = i >> 6, w = i & 63;
    float dy = sm.pre.part[0][2 * k][w] + sm.pre.part[1][2 * k][w] +
               sm.pre.part[2][2 * k][w] + sm.pre.part[3][2 * k][w];
    float dx = sm.pre.part[0][2 * k + 1][w] + sm.pre.part[1][2 * k + 1][w] +
               sm.pre.part[2][2 * k + 1][w] + sm.pre.part[3][2 * k + 1][w];
    int ky = k / 3;
    int kx = k - ky * 3;
    float py = (float)(row - 1 + ky) + dy;
    float px = (float)(w - 1 + kx) + dx;
    float y0f = floorf(py), x0f = floorf(px);
    float wy = py - y0f, wx = px - x0f;
    int y0 = (int)y0f, x0 = (int)x0f;
    int y1 = y0 + 1, x1 = x0 + 1;
    float vy0 = (y0 >= 0 && y0 < HH) ? 1.0f : 0.0f;
    float vy1 = (y1 >= 0 && y1 < HH) ? 1.0f : 0.0f;
    float vx0 = (x0 >= 0 && x0 < WW) ? 1.0f : 0.0f;
    float vx1 = (x1 >= 0 && x1 < WW) ? 1.0f : 0.0f;
    int y0c = min(max(y0, 0), HH - 1), y1c = min(max(y1, 0), HH - 1);
    int x0c = min(max(x0, 0), WW - 1), x1c = min(max(x1, 0), WW - 1);
    s_bidx[i] = make_int4((y0c * WW + x0c) * CC, (y0c * WW + x1c) * CC,
                          (y1c * WW + x0c) * CC, (y1c * WW + x1c) * CC);
    float omy = 1.0f - wy, omx = 1.0f - wx;
    s_bwt[i] = make_float4(omy * omx * vy0 * vx0, omy * wx * vy0 * vx1,
                           wy * omx * vy1 * vx0, wy * wx * vy1 * vx1);
  }
  __syncthreads();  // pre reads done before S overwrites union

  // ---- main loop ----
  const int lane = t & 63;
  const int wid  = t >> 6;
  const int sw   = t & 63;           // sampling w column
  const float* xtb = xt + (size_t)b * HWW * CC;

  f32x4 acc[2][4];
#pragma unroll
  for (int oi = 0; oi < 2; ++oi)
#pragma unroll
    for (int wt = 0; wt < 4; ++wt) acc[oi][wt] = (f32x4)0.0f;

  for (int tap = 0; tap < KK9; ++tap) {
    __syncthreads();   // prior MFMA reads of S done (first iter: phase-1 done)

    // ---- sample this tap straight into LDS (w fixed per thread, 32 ch) ----
    {
      int4   ii = s_bidx[tap * 64 + sw];
      float4 bw = s_bwt[tap * 64 + sw];
      const float* p00 = xtb + ii.x;
      const float* p01 = xtb + ii.y;
      const float* p10 = xtb + ii.z;
      const float* p11 = xtb + ii.w;
      const int c0 = wid * 32;
#pragma unroll
      for (int n = 0; n < 4; ++n) {
        int ch = c0 + n * 8;
        float4 a0 = *(const float4*)(p00 + ch), a1 = *(const float4*)(p00 + ch + 4);
        float4 b0 = *(const float4*)(p01 + ch), b1 = *(const float4*)(p01 + ch + 4);
        float4 g0 = *(const float4*)(p10 + ch), g1 = *(const float4*)(p10 + ch + 4);
        float4 d0 = *(const float4*)(p11 + ch), d1 = *(const float4*)(p11 + ch + 4);
        bf16x8 hv, lv;
#pragma unroll
        for (int j = 0; j < 4; ++j) {
          float v = bw.x * a0[j] + bw.y * b0[j] + bw.z * g0[j] + bw.w * d0[j];
          unsigned hb = bf16_rtne(v);
          float lo = v - __uint_as_float(hb << 16);
          hv[j] = (short)hb;
          lv[j] = (short)bf16_rtne(lo);
        }
#pragma unroll
        for (int j = 0; j < 4; ++j) {
          float v = bw.x * a1[j] + bw.y * b1[j] + bw.z * g1[j] + bw.w * d1[j];
          unsigned hb = bf16_rtne(v);
          float lo = v - __uint_as_float(hb << 16);
          hv[4 + j] = (short)hb;
          lv[4 + j] = (short)bf16_rtne(lo);
        }
        int cb = wid * 4 + n;                 // granule-major: S[g=cb][r=sw]
        int idx = ((cb << 6) + sw) << 3;      // wave-uniform g, r=lane: CF
        *(bf16x8*)&sm.S.hi[idx] = hv;
        *(bf16x8*)&sm.S.lo[idx] = lv;
      }
    }
    __syncthreads();   // S ready

    // ---- 4 MFMA K-steps over this tap's 128 channels, 3-term split ----
#pragma unroll
    for (int cstep = 0; cstep < 4; ++cstep) {
      int s = tap * 4 + cstep;
      bf16x8 ah[2], al[2];
#pragma unroll
      for (int oi = 0; oi < 2; ++oi) {
        size_t off = ((size_t)(s * 8 + (wid * 2 + oi)) * 64 + lane) * 8;
        ah[oi] = *(const bf16x8*)&whi[off];
        al[oi] = *(const bf16x8*)&wlo[off];
      }
      bf16x8 bh[4], bl[4];
#pragma unroll
      for (int wt = 0; wt < 4; ++wt) {
        int r = wt * 16 + (lane & 15);        // w column
        int g = cstep * 4 + (lane >> 4);      // channel granule
        int idx = ((g << 6) + r) << 3;        // granule-major read: CF
        bh[wt] = *(const bf16x8*)&sm.S.hi[idx];
        bl[wt] = *(const bf16x8*)&sm.S.lo[idx];
      }
#pragma unroll
      for (int oi = 0; oi < 2; ++oi)
#pragma unroll
        for (int wt = 0; wt < 4; ++wt) {
          acc[oi][wt] = __builtin_amdgcn_mfma_f32_16x16x32_bf16(
              ah[oi], bh[wt], acc[oi][wt], 0, 0, 0);
          acc[oi][wt] = __builtin_amdgcn_mfma_f32_16x16x32_bf16(
              ah[oi], bl[wt], acc[oi][wt], 0, 0, 0);
          acc[oi][wt] = __builtin_amdgcn_mfma_f32_16x16x32_bf16(
              al[oi], bh[wt], acc[oi][wt], 0, 0, 0);
        }
    }
  }

  // ---- epilogue: C/D layout col=lane&15, row=(lane>>4)*4+reg (m89) ----
#pragma unroll
  for (int oi = 0; oi < 2; ++oi) {
    int o = (wid * 2 + oi) * 16 + (lane >> 4) * 4;
#pragma unroll
    for (int wt = 0; wt < 4; ++wt) {
      int wcol = wt * 16 + (lane & 15);
      float* op = out + (((size_t)b * PP + o) * HH + row) * WW + wcol;
#pragma unroll
      for (int r = 0; r < 4; ++r) op[(size_t)r * HWW] = acc[oi][wt][r];
    }
  }
}

// ---------------------------------------------------------------------------
extern "C" void kernel_launch(void* const* d_in, const int* in_sizes, int n_in,
                              void* d_out, int out_size, void* d_ws, size_t ws_size,
                              hipStream_t stream) {
  const float* x     = (const float*)d_in[0];
  const float* dww   = (const float*)d_in[1];
  const float* dwb   = (const float*)d_in[2];
  const float* gamma = (const float*)d_in[3];
  const float* beta  = (const float*)d_in[4];
  const float* mean  = (const float*)d_in[5];
  const float* var   = (const float*)d_in[6];
  const float* offw  = (const float*)d_in[7];  // [18][128][1][1]
  const float* dfw   = (const float*)d_in[8];  // [128][128][3][3]
  float* out = (float*)d_out;

  // ws layout (floats): xt[4194304] | whi | wlo (147456 shorts each)
  float* xt_ws = (float*)d_ws;
  short* whi = (short*)(xt_ws + (size_t)BB * CC * HWW);
  short* wlo = whi + 36 * 8 * 64 * 8;
  k_prep<<<512 + 72, 256, 0, stream>>>(x, xt_ws, dfw, whi, wlo);
  k_deform_mfma<<<BB * HH, 256, 0, stream>>>(
      x, xt_ws, dww, dwb, gamma, beta, mean, var, offw, whi, wlo, out);
}

// Round 12
// 161.458 us; speedup vs baseline: 1.3209x; 1.3209x over previous
//
#include <hip/hip_runtime.h>

#define BB   8
#define CC   128
#define HH   64
#define WW   64
#define HWW  (HH * WW)      // 4096
#define OFFC 18
#define PP   128            // deform output channels
#define KK9  9

typedef __attribute__((ext_vector_type(8))) short bf16x8;
typedef __attribute__((ext_vector_type(4))) short sh4;
typedef __attribute__((ext_vector_type(4))) float f32x4;

// round-to-nearest-even fp32 -> bf16 bits
__device__ __forceinline__ unsigned bf16_rtne(float v) {
  unsigned u = __float_as_uint(v);
  return (u + 0x7fffu + ((u >> 16) & 1u)) >> 16;
}

// ---------------------------------------------------------------------------
// Kernel A (fused prep):
//  blocks 0..511   : transpose x [B][C][H][W] -> xt [B][H][W][C], XCD-aware
//                    (b = bid&7: xt[b] produced on the consuming XCD).
//  blocks 512..583 : pack deform weight into per-lane MFMA A-fragments,
//                    hi/lo bf16 split. K = tap*128 + c (tap-major).
//                    A-frag (16x16x32): lane l holds A[o=l&15][k=(l>>4)*8+j].
//                    Out: [kstep 36][otile 8][lane 64][8].
// ---------------------------------------------------------------------------
__global__ __launch_bounds__(256) void k_prep(
    const float* __restrict__ x, float* __restrict__ xt,
    const float* __restrict__ dfw,   // [P][C][3][3]
    short* __restrict__ whi, short* __restrict__ wlo) {
  const int t = threadIdx.x;
  if (blockIdx.x < 512) {
    __shared__ float s[CC][WW + 1];   // +1 pad
    const int b  = blockIdx.x & 7;    // XCD-local batch
    const int hh = blockIdx.x >> 3;
    const float* xp = x + (size_t)b * CC * HWW + hh * WW;
    const int w = t & 63;
#pragma unroll
    for (int p = 0; p < 32; ++p) {
      int c = p * 4 + (t >> 6);
      s[c][w] = xp[(size_t)c * HWW + w];   // coalesced 64-float rows
    }
    __syncthreads();
    float* op = xt + ((size_t)(b * HH + hh) * WW) * CC;
#pragma unroll
    for (int p = 0; p < 8; ++p) {
      int flat = p * 256 + t;            // 2048 float4 stores
      int ww = flat >> 5, cg = flat & 31;
      float4 v = make_float4(s[cg * 4][ww], s[cg * 4 + 1][ww],
                             s[cg * 4 + 2][ww], s[cg * 4 + 3][ww]);
      *(float4*)&op[ww * CC + cg * 4] = v;  // coalesced
    }
  } else {
    int tid = (blockIdx.x - 512) * 256 + t;  // 36*8*64 = 18432
    if (tid >= 36 * 8 * 64) return;
    int l  = tid & 63;
    int ot = (tid >> 6) & 7;
    int s  = tid >> 9;                 // kstep 0..35
    int o  = ot * 16 + (l & 15);
    bf16x8 hv, lv;
#pragma unroll
    for (int j = 0; j < 8; ++j) {
      int K   = s * 32 + (l >> 4) * 8 + j;
      int tap = K >> 7;
      int c   = K & 127;
      float v = dfw[((size_t)o * CC + c) * KK9 + tap];
      unsigned hb = bf16_rtne(v);
      float lo = v - __uint_as_float(hb << 16);
      hv[j] = (short)hb;
      lv[j] = (short)bf16_rtne(lo);
    }
    *(bf16x8*)&whi[(size_t)tid * 8] = hv;
    *(bf16x8*)&wlo[(size_t)tid * 8] = lv;
  }
}

// ---------------------------------------------------------------------------
// Kernel C: fused dwconv+BN+ReLU + offset 1x1 + deformable conv.
// Grid 1024: b = bid&7 (XCD pin, verified r8: FETCH 157->18.8 MB),
// rem = bid>>3: row = rem>>1, w_base = (rem&1)*32. Tile: 128o x 32w.
// LDS 33.3 KB -> 4 blocks/CU (16 waves, 2x the latency hiding of r10).
// GATHERS ARE NOW COALESCED [r10 post-mortem: 512B-strided lanes caused
// ~4x cache-line overfetch = the 146us floor]: a half-wave (32 lanes x
// float4) loads one corner-position's full 128-channel vector (512B
// contiguous); per wave-round: 2 w-positions x 4 corners.
// S layout [w][g ^ (w&7)] (16B granules): b64 writes = contiguous 256B per
// half-wave (free); b128 frag reads = 8 slots x 2 lanes per quarter-wave
// (2-way = free, m136). Swizzle identical on both sides (write w == read r).
// ---------------------------------------------------------------------------
__global__ __launch_bounds__(256) void k_deform_mfma(
    const float* __restrict__ x,     // [B][C][H][W]  (for dwconv)
    const float* __restrict__ xt,    // [B][H][W][C]  (for gathers)
    const float* __restrict__ dww,   // [C][1][3][3]
    const float* __restrict__ dwb,
    const float* __restrict__ gamma,
    const float* __restrict__ beta,
    const float* __restrict__ mean,
    const float* __restrict__ var,
    const float* __restrict__ ow,    // [18][128]
    const short* __restrict__ whi,   // packed A hi
    const short* __restrict__ wlo,   // packed A lo
    float* __restrict__ out) {       // [B][P][H][W]
  __shared__ union {
    struct {
      float part[4][OFFC][32];   //  9216 B
      float ow[OFFC * CC];       //  9216 B
      float dww[CC * KK9];       //  4608 B
      float scale[CC];           //   512 B
      float shift[CC];           //   512 B
    } pre;                                        // 24064 B
    struct { short hi[4096]; short lo[4096]; } S; // 16384 B
  } sm;
  __shared__ int4   s_bidx[288];   // 4608 B
  __shared__ float4 s_bwt[288];    // 4608 B
  // total LDS: 33280 B -> 4 blocks/CU

  const int t = threadIdx.x;
  const int b      = blockIdx.x & 7;        // XCD-local batch
  const int rem    = blockIdx.x >> 3;
  const int row    = rem >> 1;
  const int w_base = (rem & 1) << 5;

  const int lane = t & 63;
  const int wid  = t >> 6;

  // ---- phase -1: stage small weights ----
  for (int i = t; i < CC * KK9; i += 256) sm.pre.dww[i] = dww[i];
  for (int i = t; i < OFFC * CC; i += 256) sm.pre.ow[i] = ow[i];
  if (t < CC) {
    float sc = gamma[t] * rsqrtf(var[t] + 1e-5f);
    sm.pre.scale[t] = sc;
    sm.pre.shift[t] = (dwb[t] - mean[t]) * sc + beta[t];
  }
  __syncthreads();

  // ---- phase 0: h (inline dwconv+bn+relu) -> offset 1x1 partials ----
  // thread = (grp = t>>5 in 0..7 -> 16 channels, w_l = t&31). Pairs of
  // channel-groups combine via shfl_xor(32); 4 wave partials.
  {
    const int w_l = t & 31, grp = t >> 5;
    const int wg = w_base + w_l;
    const float* xb = x + (size_t)b * CC * HWW;
    float accO[OFFC];
#pragma unroll
    for (int o = 0; o < OFFC; ++o) accO[o] = 0.0f;
    for (int cc = 0; cc < 16; ++cc) {
      int c = grp * 16 + cc;
      const float* xc = xb + (size_t)c * HWW;
      float conv = 0.0f;
#pragma unroll
      for (int ky = 0; ky < 3; ++ky) {
        int y = row - 1 + ky;
        if (y < 0 || y >= HH) continue;       // block-uniform branch
        const float* xr = xc + y * WW;
#pragma unroll
        for (int kx = 0; kx < 3; ++kx) {
          int ww2 = wg - 1 + kx;
          float xv = (ww2 >= 0 && ww2 < WW) ? xr[ww2 & 63] : 0.0f;
          conv = fmaf(xv, sm.pre.dww[c * KK9 + ky * 3 + kx], conv);
        }
      }
      float hv = fmaxf(fmaf(conv, sm.pre.scale[c], sm.pre.shift[c]), 0.0f);
#pragma unroll
      for (int o = 0; o < OFFC; ++o)
        accO[o] = fmaf(hv, sm.pre.ow[o * CC + c], accO[o]);
    }
#pragma unroll
    for (int o = 0; o < OFFC; ++o) {
      accO[o] += __shfl_xor(accO[o], 32);
      if (lane < 32) sm.pre.part[wid][o][w_l] = accO[o];
    }
  }
  __syncthreads();

  // ---- phase 1: reduce partials, build bilinear tables (NHWC indices) ----
  for (int i = t; i < 288; i += 256) {
    int k = i >> 5, w_l = i & 31;
    float dy = sm.pre.part[0][2 * k][w_l] + sm.pre.part[1][2 * k][w_l] +
               sm.pre.part[2][2 * k][w_l] + sm.pre.part[3][2 * k][w_l];
    float dx = sm.pre.part[0][2 * k + 1][w_l] + sm.pre.part[1][2 * k + 1][w_l] +
               sm.pre.part[2][2 * k + 1][w_l] + sm.pre.part[3][2 * k + 1][w_l];
    int ky = k / 3;
    int kx = k - ky * 3;
    float py = (float)(row - 1 + ky) + dy;
    float px = (float)(w_base + w_l - 1 + kx) + dx;
    float y0f = floorf(py), x0f = floorf(px);
    float wy = py - y0f, wx = px - x0f;
    int y0 = (int)y0f, x0 = (int)x0f;
    int y1 = y0 + 1, x1 = x0 + 1;
    float vy0 = (y0 >= 0 && y0 < HH) ? 1.0f : 0.0f;
    float vy1 = (y1 >= 0 && y1 < HH) ? 1.0f : 0.0f;
    float vx0 = (x0 >= 0 && x0 < WW) ? 1.0f : 0.0f;
    float vx1 = (x1 >= 0 && x1 < WW) ? 1.0f : 0.0f;
    int y0c = min(max(y0, 0), HH - 1), y1c = min(max(y1, 0), HH - 1);
    int x0c = min(max(x0, 0), WW - 1), x1c = min(max(x1, 0), WW - 1);
    s_bidx[i] = make_int4((y0c * WW + x0c) * CC, (y0c * WW + x1c) * CC,
                          (y1c * WW + x0c) * CC, (y1c * WW + x1c) * CC);
    float omy = 1.0f - wy, omx = 1.0f - wx;
    s_bwt[i] = make_float4(omy * omx * vy0 * vx0, omy * wx * vy0 * vx1,
                           wy * omx * vy1 * vx0, wy * wx * vy1 * vx1);
  }
  __syncthreads();  // pre reads done before S overwrites union

  // ---- main loop ----
  const float* xtb = xt + (size_t)b * HWW * CC;
  const int hw  = lane >> 5;       // which of the 2 w-positions per round
  const int cg  = lane & 31;       // 4-channel chunk (float4) within 128
  const int gsl = cg >> 1;         // 16B granule (8 channels)
  const int ghf = cg & 1;          // half of granule

  f32x4 acc[2][2];
#pragma unroll
  for (int oi = 0; oi < 2; ++oi)
#pragma unroll
    for (int wt = 0; wt < 2; ++wt) acc[oi][wt] = (f32x4)0.0f;

  for (int tap = 0; tap < KK9; ++tap) {
    __syncthreads();   // prior MFMA reads of S done (first iter: phase-1 done)

    // ---- coalesced sampling: per round, half-wave = one corner-position's
    //      512B channel vector; 4 rounds cover this wave's 8 w-columns ----
#pragma unroll
    for (int pair = 0; pair < 4; ++pair) {
      int w_l = (wid << 3) + (pair << 1) + hw;
      int idx = tap * 32 + w_l;
      int4   ii = s_bidx[idx];
      float4 bwv = s_bwt[idx];
      float4 ca = *(const float4*)(xtb + ii.x + cg * 4);
      float4 cb = *(const float4*)(xtb + ii.y + cg * 4);
      float4 cgv = *(const float4*)(xtb + ii.z + cg * 4);
      float4 cd = *(const float4*)(xtb + ii.w + cg * 4);
      float v0 = bwv.x * ca.x + bwv.y * cb.x + bwv.z * cgv.x + bwv.w * cd.x;
      float v1 = bwv.x * ca.y + bwv.y * cb.y + bwv.z * cgv.y + bwv.w * cd.y;
      float v2 = bwv.x * ca.z + bwv.y * cb.z + bwv.z * cgv.z + bwv.w * cd.z;
      float v3 = bwv.x * ca.w + bwv.y * cb.w + bwv.z * cgv.w + bwv.w * cd.w;
      unsigned h0 = bf16_rtne(v0), h1 = bf16_rtne(v1);
      unsigned h2 = bf16_rtne(v2), h3 = bf16_rtne(v3);
      sh4 hv = {(short)h0, (short)h1, (short)h2, (short)h3};
      sh4 lv = {(short)bf16_rtne(v0 - __uint_as_float(h0 << 16)),
                (short)bf16_rtne(v1 - __uint_as_float(h1 << 16)),
                (short)bf16_rtne(v2 - __uint_as_float(h2 << 16)),
                (short)bf16_rtne(v3 - __uint_as_float(h3 << 16))};
      int si = w_l * 128 + ((gsl ^ (w_l & 7)) << 3) + (ghf << 2);
      *(sh4*)&sm.S.hi[si] = hv;
      *(sh4*)&sm.S.lo[si] = lv;
    }
    __syncthreads();   // S ready

    // ---- 4 MFMA K-steps over this tap's 128 channels, 3-term split ----
#pragma unroll
    for (int cstep = 0; cstep < 4; ++cstep) {
      int s = tap * 4 + cstep;
      bf16x8 ah[2], al[2];
#pragma unroll
      for (int oi = 0; oi < 2; ++oi) {
        size_t off = ((size_t)(s * 8 + (wid * 2 + oi)) * 64 + lane) * 8;
        ah[oi] = *(const bf16x8*)&whi[off];
        al[oi] = *(const bf16x8*)&wlo[off];
      }
      bf16x8 bh[2], bl[2];
#pragma unroll
      for (int wt = 0; wt < 2; ++wt) {
        int r = wt * 16 + (lane & 15);        // w column (0..31)
        int g = cstep * 4 + (lane >> 4);      // channel granule (0..15)
        int si = r * 128 + ((g ^ (r & 7)) << 3);
        bh[wt] = *(const bf16x8*)&sm.S.hi[si];
        bl[wt] = *(const bf16x8*)&sm.S.lo[si];
      }
#pragma unroll
      for (int oi = 0; oi < 2; ++oi)
#pragma unroll
        for (int wt = 0; wt < 2; ++wt) {
          acc[oi][wt] = __builtin_amdgcn_mfma_f32_16x16x32_bf16(
              ah[oi], bh[wt], acc[oi][wt], 0, 0, 0);
          acc[oi][wt] = __builtin_amdgcn_mfma_f32_16x16x32_bf16(
              ah[oi], bl[wt], acc[oi][wt], 0, 0, 0);
          acc[oi][wt] = __builtin_amdgcn_mfma_f32_16x16x32_bf16(
              al[oi], bh[wt], acc[oi][wt], 0, 0, 0);
        }
    }
  }

  // ---- epilogue: C/D layout col=lane&15, row=(lane>>4)*4+reg (m89) ----
#pragma unroll
  for (int oi = 0; oi < 2; ++oi) {
    int o = (wid * 2 + oi) * 16 + (lane >> 4) * 4;
#pragma unroll
    for (int wt = 0; wt < 2; ++wt) {
      int wcol = w_base + wt * 16 + (lane & 15);
      float* op = out + (((size_t)b * PP + o) * HH + row) * WW + wcol;
#pragma unroll
      for (int r = 0; r < 4; ++r) op[(size_t)r * HWW] = acc[oi][wt][r];
    }
  }
}

// ---------------------------------------------------------------------------
extern "C" void kernel_launch(void* const* d_in, const int* in_sizes, int n_in,
                              void* d_out, int out_size, void* d_ws, size_t ws_size,
                              hipStream_t stream) {
  const float* x     = (const float*)d_in[0];
  const float* dww   = (const float*)d_in[1];
  const float* dwb   = (const float*)d_in[2];
  const float* gamma = (const float*)d_in[3];
  const float* beta  = (const float*)d_in[4];
  const float* mean  = (const float*)d_in[5];
  const float* var   = (const float*)d_in[6];
  const float* offw  = (const float*)d_in[7];  // [18][128][1][1]
  const float* dfw   = (const float*)d_in[8];  // [128][128][3][3]
  float* out = (float*)d_out;

  // ws layout (floats): xt[4194304] | whi | wlo (147456 shorts each)
  float* xt_ws = (float*)d_ws;
  short* whi = (short*)(xt_ws + (size_t)BB * CC * HWW);
  short* wlo = whi + 36 * 8 * 64 * 8;
  k_prep<<<512 + 72, 256, 0, stream>>>(x, xt_ws, dfw, whi, wlo);
  k_deform_mfma<<<1024, 256, 0, stream>>>(
      x, xt_ws, dww, dwb, gamma, beta, mean, var, offw, whi, wlo, out);
}